// Round 2
// baseline (403.777 us; speedup 1.0000x reference)
//
#include <hip/hip_runtime.h>
#include <math.h>

// Problem constants (fixed by reference setup_inputs)
constexpr int B = 2, C = 16, H = 160, W = 192, S = 3, D = 48;
constexpr int HW = H * W;

__global__ __launch_bounds__(256) void plane_sweep_kernel(
    const float* __restrict__ ref_feats,   // [B,C,H,W]
    const float* __restrict__ src_feats,   // [S,B,C,H,W]
    const float* __restrict__ ref_intr,    // [B,3,3]
    const float* __restrict__ src_intr,    // [S,B,3,3]
    const float* __restrict__ ref_to_src,  // [S,B,4,4]
    const float* __restrict__ depths,      // [D]
    float* __restrict__ out)               // [B,D,H,W]
{
    const int idx = blockIdx.x * blockDim.x + threadIdx.x;
    const int total = B * D * HW;
    if (idx >= total) return;

    const int w = idx % W;
    const int h = (idx / W) % H;
    const int d = (idx / HW) % D;
    const int b = idx / (HW * D);

    // ---- double-precision 3x3 inverse of ref intrinsics (adjugate) ----
    const float* Kp = ref_intr + b * 9;
    const double a00 = Kp[0], a01 = Kp[1], a02 = Kp[2];
    const double a10 = Kp[3], a11 = Kp[4], a12 = Kp[5];
    const double a20 = Kp[6], a21 = Kp[7], a22 = Kp[8];
    const double cof00 =  (a11 * a22 - a12 * a21);
    const double cof01 = -(a10 * a22 - a12 * a20);
    const double cof02 =  (a10 * a21 - a11 * a20);
    const double cof10 = -(a01 * a22 - a02 * a21);
    const double cof11 =  (a00 * a22 - a02 * a20);
    const double cof12 = -(a00 * a21 - a01 * a20);
    const double cof20 =  (a01 * a12 - a02 * a11);
    const double cof21 = -(a00 * a12 - a02 * a10);
    const double cof22 =  (a00 * a11 - a01 * a10);
    const double det = a00 * cof00 + a01 * cof01 + a02 * cof02;
    const double invdet = 1.0 / det;
    const double i00 = cof00 * invdet, i01 = cof10 * invdet, i02 = cof20 * invdet;
    const double i10 = cof01 * invdet, i11 = cof11 * invdet, i12 = cof21 * invdet;
    const double i20 = cof02 * invdet, i21 = cof12 * invdet, i22 = cof22 * invdet;

    const double u = (double)w;
    const double v = (double)h;
    const double rayx = i00 * u + i01 * v + i02;
    const double rayy = i10 * u + i11 * v + i12;
    const double rayz = i20 * u + i21 * v + i22;

    const double depth = (double)depths[d];
    const double X0 = depth * rayx;
    const double X1 = depth * rayy;
    const double X2 = depth * rayz;

    // ---- load ref fragment, zero-mean, norm (double) ----
    double f1[C];
    const float* rp = ref_feats + (b * C) * HW + h * W + w;
    double sum1 = 0.0;
    #pragma unroll
    for (int c = 0; c < C; ++c) {
        f1[c] = (double)rp[c * HW];
        sum1 += f1[c];
    }
    const double m1 = sum1 * (1.0 / C);
    double sq1 = 0.0;
    #pragma unroll
    for (int c = 0; c < C; ++c) {
        f1[c] -= m1;
        sq1 += f1[c] * f1[c];
    }
    const double n1 = sqrt(sq1);

    double cost = 0.0;

    for (int s = 0; s < S; ++s) {
        const float* Tp  = ref_to_src + (s * B + b) * 16;
        const float* Ksp = src_intr   + (s * B + b) * 9;

        const double Xsx = (double)Tp[0] * X0 + (double)Tp[1] * X1 + (double)Tp[2]  * X2 + (double)Tp[3];
        const double Xsy = (double)Tp[4] * X0 + (double)Tp[5] * X1 + (double)Tp[6]  * X2 + (double)Tp[7];
        const double Xsz = (double)Tp[8] * X0 + (double)Tp[9] * X1 + (double)Tp[10] * X2 + (double)Tp[11];

        const double p0 = (double)Ksp[0] * Xsx + (double)Ksp[1] * Xsy + (double)Ksp[2] * Xsz;
        const double p1 = (double)Ksp[3] * Xsx + (double)Ksp[4] * Xsy + (double)Ksp[5] * Xsz;
        const double p2 = (double)Ksp[6] * Xsx + (double)Ksp[7] * Xsy + (double)Ksp[8] * Xsz;

        const bool valid = p2 > 0.001;
        const double zs = fmax(p2, 0.001);
        const double x = p0 / zs;
        const double y = p1 / zs;

        const double x0f = floor(x);
        const double y0f = floor(y);
        const double fx = x - x0f;
        const double fy = y - y0f;
        const int x0 = (int)x0f;
        const int y0 = (int)y0f;
        const int x1 = x0 + 1;
        const int y1 = y0 + 1;

        double w00 = (1.0 - fx) * (1.0 - fy);
        double w01 = fx * (1.0 - fy);
        double w10 = (1.0 - fx) * fy;
        double w11 = fx * fy;
        const bool okx0 = (x0 >= 0) && (x0 < W);
        const bool okx1 = (x1 >= 0) && (x1 < W);
        const bool oky0 = (y0 >= 0) && (y0 < H);
        const bool oky1 = (y1 >= 0) && (y1 < H);
        w00 = (valid && okx0 && oky0) ? w00 : 0.0;
        w01 = (valid && okx1 && oky0) ? w01 : 0.0;
        w10 = (valid && okx0 && oky1) ? w10 : 0.0;
        w11 = (valid && okx1 && oky1) ? w11 : 0.0;

        const int x0c = min(max(x0, 0), W - 1);
        const int x1c = min(max(x1, 0), W - 1);
        const int y0c = min(max(y0, 0), H - 1);
        const int y1c = min(max(y1, 0), H - 1);

        const int off00 = y0c * W + x0c;
        const int off01 = y0c * W + x1c;
        const int off10 = y1c * W + x0c;
        const int off11 = y1c * W + x1c;

        const float* base = src_feats + ((size_t)(s * B + b) * C) * HW;

        double f2[C];
        double sum2 = 0.0;
        #pragma unroll
        for (int c = 0; c < C; ++c) {
            const float* p = base + c * HW;
            const double v00 = (double)p[off00];
            const double v01 = (double)p[off01];
            const double v10 = (double)p[off10];
            const double v11 = (double)p[off11];
            const double val = w00 * v00 + w01 * v01 + w10 * v10 + w11 * v11;
            f2[c] = val;
            sum2 += val;
        }
        const double m2 = sum2 * (1.0 / C);
        double sq2 = 0.0;
        double dot = 0.0;
        #pragma unroll
        for (int c = 0; c < C; ++c) {
            const double f2c = f2[c] - m2;
            sq2 += f2c * f2c;
            dot += f1[c] * f2c;
        }
        const double den = n1 * sqrt(sq2) + 1e-6;
        cost += dot / den;
    }

    out[idx] = (float)(cost * (1.0 / S));
}

extern "C" void kernel_launch(void* const* d_in, const int* in_sizes, int n_in,
                              void* d_out, int out_size, void* d_ws, size_t ws_size,
                              hipStream_t stream) {
    const float* ref_feats  = (const float*)d_in[0];
    const float* src_feats  = (const float*)d_in[1];
    const float* ref_intr   = (const float*)d_in[2];
    const float* src_intr   = (const float*)d_in[3];
    const float* ref_to_src = (const float*)d_in[4];
    const float* depths     = (const float*)d_in[5];
    float* out = (float*)d_out;

    const int total = B * D * H * W;
    const int block = 256;
    const int grid = (total + block - 1) / block;
    plane_sweep_kernel<<<grid, block, 0, stream>>>(
        ref_feats, src_feats, ref_intr, src_intr, ref_to_src, depths, out);
}

// Round 3
// 183.144 us; speedup vs baseline: 2.2047x; 2.2047x over previous
//
#include <hip/hip_runtime.h>
#include <math.h>

// Problem constants (fixed by reference setup_inputs)
constexpr int B = 2, C = 16, H = 160, W = 192, S = 3, D = 48;
constexpr int HW = H * W;

__global__ __launch_bounds__(256) void plane_sweep_kernel(
    const float* __restrict__ ref_feats,   // [B,C,H,W]
    const float* __restrict__ src_feats,   // [S,B,C,H,W]
    const float* __restrict__ ref_intr,    // [B,3,3]
    const float* __restrict__ src_intr,    // [S,B,3,3]
    const float* __restrict__ ref_to_src,  // [S,B,4,4]
    const float* __restrict__ depths,      // [D]
    float* __restrict__ out)               // [B,D,H,W]
{
    const int idx = blockIdx.x * blockDim.x + threadIdx.x;
    const int total = B * D * HW;
    if (idx >= total) return;

    const int w = idx % W;
    const int h = (idx / W) % H;
    const int d = (idx / HW) % D;
    const int b = idx / (HW * D);

    // ---- double-precision 3x3 inverse of ref intrinsics (adjugate) ----
    // Geometry stays f64: x,y error is amplified by ~2/n2 (n2 as small as
    // ~7e-4 at ill-conditioned pixels); f32 geometry failed at 5.7e-2.
    const float* Kp = ref_intr + b * 9;
    const double a00 = Kp[0], a01 = Kp[1], a02 = Kp[2];
    const double a10 = Kp[3], a11 = Kp[4], a12 = Kp[5];
    const double a20 = Kp[6], a21 = Kp[7], a22 = Kp[8];
    const double cof00 =  (a11 * a22 - a12 * a21);
    const double cof01 = -(a10 * a22 - a12 * a20);
    const double cof02 =  (a10 * a21 - a11 * a20);
    const double cof10 = -(a01 * a22 - a02 * a21);
    const double cof11 =  (a00 * a22 - a02 * a20);
    const double cof12 = -(a00 * a21 - a01 * a20);
    const double cof20 =  (a01 * a12 - a02 * a11);
    const double cof21 = -(a00 * a12 - a02 * a10);
    const double cof22 =  (a00 * a11 - a01 * a10);
    const double det = a00 * cof00 + a01 * cof01 + a02 * cof02;
    const double invdet = 1.0 / det;
    const double i00 = cof00 * invdet, i01 = cof10 * invdet, i02 = cof20 * invdet;
    const double i10 = cof01 * invdet, i11 = cof11 * invdet, i12 = cof21 * invdet;
    const double i20 = cof02 * invdet, i21 = cof12 * invdet, i22 = cof22 * invdet;

    const double u = (double)w;
    const double v = (double)h;
    const double rayx = i00 * u + i01 * v + i02;
    const double rayy = i10 * u + i11 * v + i12;
    const double rayz = i20 * u + i21 * v + i22;

    const double depth = (double)depths[d];
    const double X0 = depth * rayx;
    const double X1 = depth * rayy;
    const double X2 = depth * rayz;

    // ---- load ref fragment, zero-mean, norm (f32 — well-conditioned: n1^2 ~ C) ----
    float f1[C];
    const float* rp = ref_feats + (b * C) * HW + h * W + w;
    float sum1 = 0.0f;
    #pragma unroll
    for (int c = 0; c < C; ++c) {
        f1[c] = rp[c * HW];
        sum1 += f1[c];
    }
    const float m1 = sum1 * (1.0f / C);
    float sq1 = 0.0f;
    #pragma unroll
    for (int c = 0; c < C; ++c) {
        f1[c] -= m1;
        sq1 += f1[c] * f1[c];
    }
    const float n1 = sqrtf(sq1);

    float cost = 0.0f;

    for (int s = 0; s < S; ++s) {
        const float* Tp  = ref_to_src + (s * B + b) * 16;
        const float* Ksp = src_intr   + (s * B + b) * 9;

        const double Xsx = (double)Tp[0] * X0 + (double)Tp[1] * X1 + (double)Tp[2]  * X2 + (double)Tp[3];
        const double Xsy = (double)Tp[4] * X0 + (double)Tp[5] * X1 + (double)Tp[6]  * X2 + (double)Tp[7];
        const double Xsz = (double)Tp[8] * X0 + (double)Tp[9] * X1 + (double)Tp[10] * X2 + (double)Tp[11];

        const double p0 = (double)Ksp[0] * Xsx + (double)Ksp[1] * Xsy + (double)Ksp[2] * Xsz;
        const double p1 = (double)Ksp[3] * Xsx + (double)Ksp[4] * Xsy + (double)Ksp[5] * Xsz;
        const double p2 = (double)Ksp[6] * Xsx + (double)Ksp[7] * Xsy + (double)Ksp[8] * Xsz;

        const bool valid = p2 > 0.001;
        const double zs = fmax(p2, 0.001);
        const double invz = 1.0 / zs;
        const double x = p0 * invz;
        const double y = p1 * invz;

        const double x0f = floor(x);
        const double y0f = floor(y);
        const double fx = x - x0f;
        const double fy = y - y0f;
        const int x0 = (int)x0f;
        const int y0 = (int)y0f;
        const int x1 = x0 + 1;
        const int y1 = y0 + 1;

        // weights in f64, then rounded to f32 (error ~6e-8, amplified to ~1e-4 worst case)
        double dw00 = (1.0 - fx) * (1.0 - fy);
        double dw01 = fx * (1.0 - fy);
        double dw10 = (1.0 - fx) * fy;
        double dw11 = fx * fy;
        const bool okx0 = (x0 >= 0) && (x0 < W);
        const bool okx1 = (x1 >= 0) && (x1 < W);
        const bool oky0 = (y0 >= 0) && (y0 < H);
        const bool oky1 = (y1 >= 0) && (y1 < H);
        const float w00 = (float)((valid && okx0 && oky0) ? dw00 : 0.0);
        const float w01 = (float)((valid && okx1 && oky0) ? dw01 : 0.0);
        const float w10 = (float)((valid && okx0 && oky1) ? dw10 : 0.0);
        const float w11 = (float)((valid && okx1 && oky1) ? dw11 : 0.0);

        const int x0c = min(max(x0, 0), W - 1);
        const int x1c = min(max(x1, 0), W - 1);
        const int y0c = min(max(y0, 0), H - 1);
        const int y1c = min(max(y1, 0), H - 1);

        const int off00 = y0c * W + x0c;
        const int off01 = y0c * W + x1c;
        const int off10 = y1c * W + x0c;
        const int off11 = y1c * W + x1c;

        const float* base = src_feats + ((size_t)(s * B + b) * C) * HW;

        // pass 1: bilinear + sum (f32)
        float f2[C];
        float sum2 = 0.0f;
        #pragma unroll
        for (int c = 0; c < C; ++c) {
            const float* p = base + c * HW;
            const float v00 = p[off00];
            const float v01 = p[off01];
            const float v10 = p[off10];
            const float v11 = p[off11];
            const float val = w00 * v00 + w01 * v01 + w10 * v10 + w11 * v11;
            f2[c] = val;
            sum2 += val;
        }
        // pass 2: mean-subtracted NCC reduction (f32)
        const float m2 = sum2 * (1.0f / C);
        float sq2 = 0.0f;
        float dot = 0.0f;
        #pragma unroll
        for (int c = 0; c < C; ++c) {
            const float f2c = f2[c] - m2;
            sq2 = fmaf(f2c, f2c, sq2);
            dot = fmaf(f1[c], f2c, dot);
        }
        const float den = n1 * sqrtf(sq2) + 1e-6f;
        cost += dot / den;
    }

    out[idx] = cost * (1.0f / S);
}

extern "C" void kernel_launch(void* const* d_in, const int* in_sizes, int n_in,
                              void* d_out, int out_size, void* d_ws, size_t ws_size,
                              hipStream_t stream) {
    const float* ref_feats  = (const float*)d_in[0];
    const float* src_feats  = (const float*)d_in[1];
    const float* ref_intr   = (const float*)d_in[2];
    const float* src_intr   = (const float*)d_in[3];
    const float* ref_to_src = (const float*)d_in[4];
    const float* depths     = (const float*)d_in[5];
    float* out = (float*)d_out;

    const int total = B * D * H * W;
    const int block = 256;
    const int grid = (total + block - 1) / block;
    plane_sweep_kernel<<<grid, block, 0, stream>>>(
        ref_feats, src_feats, ref_intr, src_intr, ref_to_src, depths, out);
}